// Round 9
// baseline (298.488 us; speedup 1.0000x reference)
//
#include <hip/hip_runtime.h>
#include <cmath>

constexpr int S_LEN = 2048;
constexpr float EPS = 1e-8f;

typedef unsigned uvec32 __attribute__((ext_vector_type(32)));

__device__ __forceinline__ float fin(float v) { return isfinite(v) ? v : 0.0f; }
__device__ __forceinline__ float rcpf(float x) { return __builtin_amdgcn_rcpf(x); }

__device__ __forceinline__ unsigned f2o_bits(unsigned u) {
    return (u & 0x80000000u) ? ~u : (u | 0x80000000u);
}
__device__ __forceinline__ float o2f(unsigned u) {
    return __uint_as_float((u & 0x80000000u) ? (u ^ 0x80000000u) : ~u);
}

// ---- DPP helpers ----
template <int Ctrl, int Rmask>
__device__ __forceinline__ int dpp_zero_i(int x) {
    return __builtin_amdgcn_update_dpp(0, x, Ctrl, Rmask, 0xF, true);
}
template <int Ctrl>
__device__ __forceinline__ int dpp_keep_i(int x) {
    return __builtin_amdgcn_update_dpp(x, x, Ctrl, 0xF, 0xF, false);
}
__device__ __forceinline__ float dpp_shdn1_f(float x) {
    return __uint_as_float((unsigned)dpp_zero_i<0x130, 0xF>((int)__float_as_uint(x)));
}
__device__ __forceinline__ int wred_add_i(int v) {
    v += dpp_zero_i<0xB1, 0xF>(v);
    v += dpp_zero_i<0x4E, 0xF>(v);
    v += dpp_zero_i<0x114, 0xF>(v);
    v += dpp_zero_i<0x118, 0xF>(v);
    v += dpp_zero_i<0x142, 0xA>(v);
    v += dpp_zero_i<0x143, 0xC>(v);
    return __builtin_amdgcn_readlane(v, 63);
}
__device__ __forceinline__ float wred_add_f(float v) {
    #define ADDF(CT, RM) v += __uint_as_float((unsigned)dpp_zero_i<CT, RM>((int)__float_as_uint(v)))
    ADDF(0xB1, 0xF); ADDF(0x4E, 0xF); ADDF(0x114, 0xF);
    ADDF(0x118, 0xF); ADDF(0x142, 0xA); ADDF(0x143, 0xC);
    #undef ADDF
    return __uint_as_float((unsigned)__builtin_amdgcn_readlane((int)__float_as_uint(v), 63));
}
__device__ __forceinline__ float wred_min_f(float v) {
    #define MINF(CT) v = fminf(v, __uint_as_float((unsigned)dpp_keep_i<CT>((int)__float_as_uint(v))))
    MINF(0xB1); MINF(0x4E); MINF(0x114); MINF(0x118); MINF(0x142); MINF(0x143);
    #undef MINF
    return __uint_as_float((unsigned)__builtin_amdgcn_readlane((int)__float_as_uint(v), 63));
}
__device__ __forceinline__ float wred_max_f(float v) {
    #define MAXF(CT) v = fmaxf(v, __uint_as_float((unsigned)dpp_keep_i<CT>((int)__float_as_uint(v))))
    MAXF(0xB1); MAXF(0x4E); MAXF(0x114); MAXF(0x118); MAXF(0x142); MAXF(0x143);
    #undef MAXF
    return __uint_as_float((unsigned)__builtin_amdgcn_readlane((int)__float_as_uint(v), 63));
}
__device__ __forceinline__ unsigned wred_umin(unsigned v) {
    #define MINU(CT) { unsigned t = (unsigned)dpp_keep_i<CT>((int)v); v = v < t ? v : t; }
    MINU(0xB1) MINU(0x4E) MINU(0x114) MINU(0x118) MINU(0x142) MINU(0x143)
    #undef MINU
    return (unsigned)__builtin_amdgcn_readlane((int)v, 63);
}
__device__ __forceinline__ float readlane_f(float x, int l) {
    return __uint_as_float((unsigned)__builtin_amdgcn_readlane((int)__float_as_uint(x), l));
}

// Hacker's Delight 32x32 bit transpose (anti-diagonal; involution).
__device__ __forceinline__ void transpose32(uvec32& A) {
    #pragma unroll
    for (int k = 0; k < 16; k++) {
        unsigned lo = __builtin_amdgcn_perm(A[k], A[k + 16], 0x07060302u);
        unsigned hi = __builtin_amdgcn_perm(A[k], A[k + 16], 0x05040100u);
        A[k] = lo; A[k + 16] = hi;
    }
    #pragma unroll
    for (int k0 = 0; k0 < 32; k0 += 16) {
        #pragma unroll
        for (int k = k0; k < k0 + 8; k++) {
            unsigned lo = __builtin_amdgcn_perm(A[k], A[k + 8], 0x07030501u);
            unsigned hi = __builtin_amdgcn_perm(A[k], A[k + 8], 0x06020400u);
            A[k] = lo; A[k + 8] = hi;
        }
    }
    #pragma unroll
    for (int j = 4; j; j >>= 1) {
        const unsigned m = (j == 4) ? 0x0F0F0F0Fu : (j == 2) ? 0x33333333u : 0x55555555u;
        #pragma unroll
        for (int k = 0; k < 32; k++) {
            if (!(k & j)) {
                unsigned Ak = A[k], Bk = A[k | j];
                A[k]     = ((Bk >> j) & m) | (Ak & ~m);
                A[k | j] = ((Ak << j) & ~m) | (Bk & m);
            }
        }
    }
}

#define AF(e) __uint_as_float(a[e])

// Phase-1 streaming stats for one row held in `a`; writes 16 features to s[].
__device__ __forceinline__ void phase1_stats(const uvec32& a, float* s, int lane) {
    float s1 = 0.f, s2 = 0.f, s3 = 0.f, s4 = 0.f, sd2 = 0.f, sad = 0.f;
    float p1 = 0.f, p7 = 0.f, p24 = 0.f, se1 = 0.f, se2 = 0.f;
    float mn = AF(0), mx = AF(0);
    #pragma unroll
    for (int e = 0; e < 32; e++) {
        float val = AF(e);
        float t = val * val;
        s1 += val; s2 += t;
        s3 = fmaf(t, val, s3); s4 = fmaf(t, t, s4);
        mn = fminf(mn, val); mx = fmaxf(mx, val);
    }
    #pragma unroll
    for (int e = 0; e < 31; e++) {
        float d = AF(e + 1) - AF(e);
        sd2 = fmaf(d, d, sd2); sad += fabsf(d);
        p1 = fmaf(AF(e), AF(e + 1), p1);
    }
    #pragma unroll
    for (int e = 0; e < 25; e++) p7 = fmaf(AF(e), AF(e + 7), p7);
    #pragma unroll
    for (int e = 0; e < 8; e++)  p24 = fmaf(AF(e), AF(e + 24), p24);

    const bool notlast = (lane < 63);
    #pragma unroll
    for (int j = 0; j < 24; j++) {
        float g = dpp_shdn1_f(AF(j));          // lane 63 -> 0
        p24 = fmaf(AF(8 + j), g, p24);
        if (j < 7) p7 = fmaf(AF(25 + j), g, p7);
        if (j == 0) {
            float d = g - AF(31);
            float dm = notlast ? d : 0.f;
            sd2 = fmaf(dm, dm, sd2); sad += fabsf(dm);
            p1 = fmaf(AF(31), g, p1);
        }
    }
    {   // seasonal x[::24]
        int r3 = lane % 3;
        float sv = (r3 == 0) ? AF(0) : ((r3 == 1) ? AF(16) : AF(8));
        se1 += sv; se2 = fmaf(sv, sv, se2);
        if (r3 == 0) { se1 += AF(24); se2 = fmaf(AF(24), AF(24), se2); }
    }
    const bool is63 = (lane == 63);
    float acc1 = 0.f, acc2 = 0.f, ck1 = 0.f, ck2 = 0.f;
    #pragma unroll
    for (int i = 0; i < 24; i++) {
        float pick = is63 ? AF(31 - i) : AF(i);
        acc1 += pick; acc2 = fmaf(pick, pick, acc2);
        if (i == 6) { ck1 = acc1; ck2 = acc2; }
    }
    const float h1  = readlane_f(AF(0), 0),   t1  = readlane_f(AF(31), 63);
    const float h7  = readlane_f(ck1, 0),     hq7 = readlane_f(ck2, 0);
    const float h24 = readlane_f(acc1, 0),    hq24 = readlane_f(acc2, 0);
    const float t7  = readlane_f(ck1, 63),    tq7 = readlane_f(ck2, 63);
    const float t24 = readlane_f(acc1, 63),   tq24 = readlane_f(acc2, 63);
    const float hq1 = h1 * h1, tq1 = t1 * t1;

    float S1  = wred_add_f(s1);
    float S2  = wred_add_f(s2);
    float S3  = wred_add_f(s3);
    float S4  = wred_add_f(s4);
    float SD2 = wred_add_f(sd2);
    float SAD = wred_add_f(sad);
    float P1  = wred_add_f(p1);
    float P7  = wred_add_f(p7);
    float P24 = wred_add_f(p24);
    float SE1 = wred_add_f(se1);
    float SE2 = wred_add_f(se2);
    float MN  = wred_min_f(mn);
    float MX  = wred_max_f(mx);

    constexpr float invS  = 1.0f / 2048.0f;   // exact (pow2)
    constexpr float invND = 1.0f / 2047.0f;
    const float Sf = (float)S_LEN;
    float mu = S1 * invS;
    float q2 = S2 * invS, q3 = S3 * invS, q4 = S4 * invS;
    float mu2 = mu * mu;
    float m2v = q2 - mu2;
    float m3v = q3 - 3.f * mu * q2 + 2.f * mu * mu2;
    float m4v = q4 - 4.f * mu * q3 + 6.f * mu2 * q2 - 3.f * mu2 * mu2;
    float stdv = sqrtf(m2v);
    float dmean = (t1 - h1) * invND;
    float dvar = SD2 * invND - dmean * dmean;
    float std_diff = sqrtf(fmaxf(dvar, 0.f));
    float trend = std_diff * rcpf(stdv + EPS);
    float ac[3];
    const float invN[3] = {1.0f / 2047.0f, 1.0f / 2041.0f, 1.0f / 2024.0f};
    const float Ps[3] = {P1, P7, P24};
    const float hd[3] = {h1, h7, h24},   hqv[3] = {hq1, hq7, hq24};
    const float tl[3] = {t1, t7, t24},   tqv[3] = {tq1, tq7, tq24};
    #pragma unroll
    for (int q = 0; q < 3; q++) {
        float in = invN[q];
        float sa = S1 - tl[q], sb = S1 - hd[q];
        float qa = S2 - tqv[q], qb = S2 - hqv[q];
        float am = sa * in, bm = sb * in;
        float cov = Ps[q] * in - am * bm;
        float as_ = sqrtf(fmaxf(qa * in - am * am, 0.f));
        float bs_ = sqrtf(fmaxf(qb * in - bm * bm, 0.f));
        ac[q] = cov * rcpf(as_ * bs_);
    }
    float cv = stdv * rcpf(fabsf(mu) + EPS);
    float sm = SE1 * (1.0f / 86.0f);
    float svar = SE2 * (1.0f / 86.0f) - sm * sm;
    float seasonal = svar * rcpf(m2v + EPS);
    float skew = m3v * rcpf(m2v * stdv);
    float kurt = m4v * rcpf(m2v * m2v) - 3.f;
    if (lane == 0) {
        s[0]  = fin(mu);       s[1]  = fin(stdv);
        s[2]  = fin(MN);       s[3]  = fin(MX);
        s[5]  = fin(trend);    s[6]  = fin(ac[0]);
        s[7]  = fin(ac[1]);    s[8]  = fin(ac[2]);
        s[9]  = fin(cv);       s[11] = fin(seasonal);
        s[12] = fin(skew);     s[13] = fin(kurt);
        s[14] = Sf;            s[15] = fin(SAD);
        s[16] = fin(SAD * invND); s[17] = fin(std_diff);
    }
}

// Per-row MLP: h = relu(f @ W1T + b1); out = h @ W2^T + b2.
__device__ __forceinline__ void mlp_row(
    const float* __restrict__ wt, const float* __restrict__ b1,
    const float* __restrict__ W2, const float* __restrict__ b2,
    const float* sfrow, float* hrow, float* __restrict__ outrow, int lane)
{
    const float4* sfv = (const float4*)sfrow;
    float4 f0 = sfv[0], f1 = sfv[1], f2 = sfv[2], f3 = sfv[3], f4 = sfv[4];
    float h = b1[lane];
    h = fmaf(f0.x, wt[ 0 * 64 + lane], h);
    h = fmaf(f0.y, wt[ 1 * 64 + lane], h);
    h = fmaf(f0.z, wt[ 2 * 64 + lane], h);
    h = fmaf(f0.w, wt[ 3 * 64 + lane], h);
    h = fmaf(f1.x, wt[ 4 * 64 + lane], h);
    h = fmaf(f1.y, wt[ 5 * 64 + lane], h);
    h = fmaf(f1.z, wt[ 6 * 64 + lane], h);
    h = fmaf(f1.w, wt[ 7 * 64 + lane], h);
    h = fmaf(f2.x, wt[ 8 * 64 + lane], h);
    h = fmaf(f2.y, wt[ 9 * 64 + lane], h);
    h = fmaf(f2.z, wt[10 * 64 + lane], h);
    h = fmaf(f2.w, wt[11 * 64 + lane], h);
    h = fmaf(f3.x, wt[12 * 64 + lane], h);
    h = fmaf(f3.y, wt[13 * 64 + lane], h);
    h = fmaf(f3.z, wt[14 * 64 + lane], h);
    h = fmaf(f3.w, wt[15 * 64 + lane], h);
    h = fmaf(f4.x, wt[16 * 64 + lane], h);
    h = fmaf(f4.y, wt[17 * 64 + lane], h);
    h = fmaf(f4.z, wt[18 * 64 + lane], h);
    h = fmaf(f4.w, wt[19 * 64 + lane], h);
    h = fmaxf(h, 0.f);
    hrow[lane] = h;
    __asm__ volatile("s_waitcnt lgkmcnt(0)" ::: "memory");
    __builtin_amdgcn_sched_barrier(0);

    const int j2 = lane * 2;
    float2 b2v = *(const float2*)(b2 + j2);
    float acc0 = b2v.x, acc1b = b2v.y;
    const float4* w2r0 = (const float4*)(W2 + (size_t)j2 * 64);
    const float4* w2r1 = (const float4*)(W2 + (size_t)(j2 + 1) * 64);
    const float4* hv4 = (const float4*)hrow;
    #pragma unroll
    for (int q = 0; q < 16; q++) {
        float4 hq = hv4[q];
        float4 wa = w2r0[q];
        float4 wb = w2r1[q];
        acc0 = fmaf(hq.x, wa.x, acc0); acc1b = fmaf(hq.x, wb.x, acc1b);
        acc0 = fmaf(hq.y, wa.y, acc0); acc1b = fmaf(hq.y, wb.y, acc1b);
        acc0 = fmaf(hq.z, wa.z, acc0); acc1b = fmaf(hq.z, wb.z, acc1b);
        acc0 = fmaf(hq.w, wa.w, acc0); acc1b = fmaf(hq.w, wb.w, acc1b);
    }
    *(float2*)(outrow + j2) = make_float2(acc0, acc1b);
}

// ============ K0: transpose W1 once into d_ws ============
__global__ __launch_bounds__(256) void transpose_w_kernel(
    const float* __restrict__ W1, float* __restrict__ wt)
{
    int tid = blockIdx.x * blockDim.x + threadIdx.x;
    int stride = gridDim.x * blockDim.x;
    for (int n = tid; n < 64 * 20; n += stride) {
        int j = n & 63, k = n >> 6;
        wt[n] = W1[j * 20 + k];
    }
}

// ============ K1: 2 rows per wave; radix+scans interleaved for ILP ============
__global__ __launch_bounds__(256, 4) void fused_stats_mlp_kernel(
    const float* __restrict__ x, const float* __restrict__ wt,
    const float* __restrict__ b1, const float* __restrict__ W2,
    const float* __restrict__ b2, float* __restrict__ out, int nrows)
{
    __shared__ __align__(16) float sf[4][2][20];
    __shared__ __align__(16) float hsh[4][2][64];

    const int lane = threadIdx.x & 63;
    const int w    = threadIdx.x >> 6;
    int base = (blockIdx.x * 4 + w) * 2;
    int r0 = min(base, nrows - 1);
    int r1 = min(base + 1, nrows - 1);

    uvec32 a, c;
    const float* xr0 = x + (size_t)r0 * S_LEN + lane * 32;
    const float* xr1 = x + (size_t)r1 * S_LEN + lane * 32;
    #pragma unroll
    for (int q = 0; q < 8; q++) {
        float4 t = reinterpret_cast<const float4*>(xr0)[q];
        a[4 * q + 0] = __float_as_uint(t.x); a[4 * q + 1] = __float_as_uint(t.y);
        a[4 * q + 2] = __float_as_uint(t.z); a[4 * q + 3] = __float_as_uint(t.w);
    }
    #pragma unroll
    for (int q = 0; q < 8; q++) {
        float4 t = reinterpret_cast<const float4*>(xr1)[q];
        c[4 * q + 0] = __float_as_uint(t.x); c[4 * q + 1] = __float_as_uint(t.y);
        c[4 * q + 2] = __float_as_uint(t.z); c[4 * q + 3] = __float_as_uint(t.w);
    }

    phase1_stats(a, sf[w][0], lane);
    phase1_stats(c, sf[w][1], lane);

    // ---------------- phase 2: both rows, interleaved ----------------
    #pragma unroll
    for (int e = 0; e < 32; e++) { a[e] = f2o_bits(a[e]); c[e] = f2o_bits(c[e]); }
    transpose32(a);
    transpose32(c);

    unsigned actA0 = ~0u, actA1 = ~0u, actA2 = ~0u;
    unsigned actB0 = ~0u, actB1 = ~0u, actB2 = ~0u;
    int KA0 = 511, KA1 = 1023, KA2 = 1535;
    int KB0 = 511, KB1 = 1023, KB2 = 1535;
    int cA0 = 2048, cA1 = 2048, cA2 = 2048;
    int cB0 = 2048, cB1 = 2048, cB2 = 2048;
    unsigned uA0 = 0, uA1 = 0, uA2 = 0;
    unsigned uB0 = 0, uB1 = 0, uB2 = 0;
    bool alldone = false;
    #pragma unroll
    for (int b = 31; b >= 0; b--) {
        if (!alldone) {
            unsigned mbA = a[31 - b];
            unsigned mbB = c[31 - b];
            unsigned wA0 = actA0 & mbA, wA1 = actA1 & mbA, wA2 = actA2 & mbA;
            unsigned wB0 = actB0 & mbB, wB1 = actB1 & mbB, wB2 = actB2 & mbB;
            int OA01 = wred_add_i(__popc(wA0) | (__popc(wA1) << 16));
            int OB01 = wred_add_i(__popc(wB0) | (__popc(wB1) << 16));
            int OA2  = wred_add_i(__popc(wA2));
            int OB2  = wred_add_i(__popc(wB2));
            int zA0 = cA0 - (OA01 & 0xFFFF);
            int zA1 = cA1 - (int)((unsigned)OA01 >> 16);
            int zA2 = cA2 - OA2;
            int zB0 = cB0 - (OB01 & 0xFFFF);
            int zB1 = cB1 - (int)((unsigned)OB01 >> 16);
            int zB2 = cB2 - OB2;
            bool tA0 = (KA0 >= zA0), tA1 = (KA1 >= zA1), tA2 = (KA2 >= zA2);
            bool tB0 = (KB0 >= zB0), tB1 = (KB1 >= zB1), tB2 = (KB2 >= zB2);
            actA0 = tA0 ? wA0 : (actA0 ^ wA0);
            actA1 = tA1 ? wA1 : (actA1 ^ wA1);
            actA2 = tA2 ? wA2 : (actA2 ^ wA2);
            actB0 = tB0 ? wB0 : (actB0 ^ wB0);
            actB1 = tB1 ? wB1 : (actB1 ^ wB1);
            actB2 = tB2 ? wB2 : (actB2 ^ wB2);
            cA0 = tA0 ? (cA0 - zA0) : zA0;
            cA1 = tA1 ? (cA1 - zA1) : zA1;
            cA2 = tA2 ? (cA2 - zA2) : zA2;
            cB0 = tB0 ? (cB0 - zB0) : zB0;
            cB1 = tB1 ? (cB1 - zB1) : zB1;
            cB2 = tB2 ? (cB2 - zB2) : zB2;
            KA0 = tA0 ? (KA0 - zA0) : KA0;
            KA1 = tA1 ? (KA1 - zA1) : KA1;
            KA2 = tA2 ? (KA2 - zA2) : KA2;
            KB0 = tB0 ? (KB0 - zB0) : KB0;
            KB1 = tB1 ? (KB1 - zB1) : KB1;
            KB2 = tB2 ? (KB2 - zB2) : KB2;
            uA0 |= tA0 ? (1u << b) : 0u;
            uA1 |= tA1 ? (1u << b) : 0u;
            uA2 |= tA2 ? (1u << b) : 0u;
            uB0 |= tB0 ? (1u << b) : 0u;
            uB1 |= tB1 ? (1u << b) : 0u;
            uB2 |= tB2 ? (1u << b) : 0u;
            alldone = (cA0 == 1) && (cA1 == 1) && (cA2 == 1) &&
                      (cB0 == 1) && (cB1 == 1) && (cB2 == 1);
        }
    }
    const int eA0 = cA0, eA1 = cA1, eA2 = cA2;
    const int eB0 = cB0, eB1 = cB1, eB2 = cB2;

    transpose32(a);   // involution -> recover orderable values
    transpose32(c);

    // survivor = min{ue >= uK_prefix} via wrap-around (full run: min d = 0)
    {
        unsigned dA0 = ~0u, dA1 = ~0u, dA2 = ~0u;
        unsigned dB0 = ~0u, dB1 = ~0u, dB2 = ~0u;
        #pragma unroll
        for (int e = 0; e < 32; e++) {
            unsigned ua = a[e], uc = c[e];
            unsigned t0 = ua - uA0; dA0 = dA0 < t0 ? dA0 : t0;
            unsigned t1 = ua - uA1; dA1 = dA1 < t1 ? dA1 : t1;
            unsigned t2 = ua - uA2; dA2 = dA2 < t2 ? dA2 : t2;
            unsigned t3 = uc - uB0; dB0 = dB0 < t3 ? dB0 : t3;
            unsigned t4 = uc - uB1; dB1 = dB1 < t4 ? dB1 : t4;
            unsigned t5 = uc - uB2; dB2 = dB2 < t5 ? dB2 : t5;
        }
        uA0 += wred_umin(dA0);
        uB0 += wred_umin(dB0);
        uA1 += wred_umin(dA1);
        uB1 += wred_umin(dB1);
        uA2 += wred_umin(dA2);
        uB2 += wred_umin(dB2);
    }

    // successor = min{ue > uK} via wrap-around
    const unsigned kA0 = uA0 + 1, kA1 = uA1 + 1, kA2 = uA2 + 1;
    const unsigned kB0 = uB0 + 1, kB1 = uB1 + 1, kB2 = uB2 + 1;
    unsigned mA0 = ~0u, mA1 = ~0u, mA2 = ~0u;
    unsigned mB0 = ~0u, mB1 = ~0u, mB2 = ~0u;
    #pragma unroll
    for (int e = 0; e < 32; e++) {
        unsigned ua = a[e], uc = c[e];
        unsigned t0 = ua - kA0; mA0 = mA0 < t0 ? mA0 : t0;
        unsigned t1 = ua - kA1; mA1 = mA1 < t1 ? mA1 : t1;
        unsigned t2 = ua - kA2; mA2 = mA2 < t2 ? mA2 : t2;
        unsigned t3 = uc - kB0; mB0 = mB0 < t3 ? mB0 : t3;
        unsigned t4 = uc - kB1; mB1 = mB1 < t4 ? mB1 : t4;
        unsigned t5 = uc - kB2; mB2 = mB2 < t5 ? mB2 : t5;
    }
    mA0 = wred_umin(mA0) + kA0;
    mB0 = wred_umin(mB0) + kB0;
    mA1 = wred_umin(mA1) + kA1;
    mB1 = wred_umin(mB1) + kB1;
    mA2 = wred_umin(mA2) + kA2;
    mB2 = wred_umin(mB2) + kB2;

    if (lane == 0) {
        {
            float v511 = o2f(uA0), v1023 = o2f(uA1), v1535 = o2f(uA2);
            float v512  = (KA0 + 1 < eA0) ? v511  : o2f(mA0);
            float v1024 = (KA1 + 1 < eA1) ? v1023 : o2f(mA1);
            float v1536 = (KA2 + 1 < eA2) ? v1535 : o2f(mA2);
            float p25 = v511 + 0.75f * (v512 - v511);
            float med = 0.5f * (v1023 + v1024);
            float p75 = v1535 + 0.25f * (v1536 - v1535);
            float* s = sf[w][0];
            s[4]  = fin(med); s[10] = fin(p75 - p25);
            s[18] = fin(p25); s[19] = fin(p75);
        }
        {
            float v511 = o2f(uB0), v1023 = o2f(uB1), v1535 = o2f(uB2);
            float v512  = (KB0 + 1 < eB0) ? v511  : o2f(mB0);
            float v1024 = (KB1 + 1 < eB1) ? v1023 : o2f(mB1);
            float v1536 = (KB2 + 1 < eB2) ? v1535 : o2f(mB2);
            float p25 = v511 + 0.75f * (v512 - v511);
            float med = 0.5f * (v1023 + v1024);
            float p75 = v1535 + 0.25f * (v1536 - v1535);
            float* s = sf[w][1];
            s[4]  = fin(med); s[10] = fin(p75 - p25);
            s[18] = fin(p25); s[19] = fin(p75);
        }
    }
    // Intra-wave LDS visibility: wave is lockstep, only a waitcnt is needed.
    __asm__ volatile("s_waitcnt lgkmcnt(0)" ::: "memory");
    __builtin_amdgcn_sched_barrier(0);

    // ---------------- phase 3: MLP for both rows ----------------
    mlp_row(wt, b1, W2, b2, sf[w][0], hsh[w][0], out + (size_t)r0 * 128, lane);
    mlp_row(wt, b1, W2, b2, sf[w][1], hsh[w][1], out + (size_t)r1 * 128, lane);
}

extern "C" void kernel_launch(void* const* d_in, const int* in_sizes, int n_in,
                              void* d_out, int out_size, void* d_ws, size_t ws_size,
                              hipStream_t stream) {
    const float* x  = (const float*)d_in[0];
    const float* W1 = (const float*)d_in[1];
    const float* b1 = (const float*)d_in[2];
    const float* W2 = (const float*)d_in[3];
    const float* b2 = (const float*)d_in[4];
    float* out = (float*)d_out;
    float* wt  = (float*)d_ws;       // 1280 floats: W1T
    int nrows = in_sizes[0] / S_LEN;
    int blocks = (nrows + 7) / 8;    // 4 waves/block, 2 rows per wave
    transpose_w_kernel<<<2, 256, 0, stream>>>(W1, wt);
    fused_stats_mlp_kernel<<<blocks, 256, 0, stream>>>(x, wt, b1, W2, b2, out, nrows);
}